// Round 18
// baseline (11902.950 us; speedup 1.0000x reference)
//
#include <hip/hip_runtime.h>
#include <stdint.h>

// ---------------------------------------------------------------------------
// 2-layer BiLSTM LM: emb -> BiLSTM(E=256->H=512) -> BiLSTM(1024->512) -> proj
// V=128 E=256 H=512 B=128 T=512.
//
// Round 18: ROLLBACK + composition of r13-validated cells.
//  r15/r16/r17 post-mortem: identical absmax under different coherence
//  schemes => deterministic mapping bug in the r15 partition; abandoned.
//  This kernel = r13's source (which PASSED end-to-end) with:
//   - single dispatch per layer (s0=0..TT, no cbuf)
//   - HMODE=1 everywhere: h via sc1 u64 atomic loads, ZERO per-step
//     invalidates -> L1's hseq x-reads (read-only, 16MB/step) stay
//     L2-resident instead of LLC-re-fetched (r10's per-step inv wiped them).
//   - BMODE=1 everywhere: scope-64 (same dir,mh) busy-poll flag wait
//     (r13 L1-D2 validated; exact-dependency scope).
//  proj every 64 steps keeps its ACQUIRE-inv (r10/r13-proven; all data it
//  exposes is sc1-written ring or read-only weights -> inv-safe).
//
// Numerics (validated r1..r13, absmax 1.95e-3): bf16 MFMA fp32-accum; c f32;
// h carried as hi/lo bf16 planes; gates = Whh*(hi+lo) + Wih*x + b.
// ---------------------------------------------------------------------------

#define TT 512
#define BB 128
#define HH 512
#define VV 128
#define AGENT __HIP_MEMORY_SCOPE_AGENT

typedef __attribute__((ext_vector_type(8))) short bf16x8;
typedef __attribute__((ext_vector_type(4))) float f32x4;

__device__ __forceinline__ ushort f2bf(float f) {
  uint32_t u = __builtin_bit_cast(uint32_t, f);
  u += 0x7FFFu + ((u >> 16) & 1u);
  return (ushort)(u >> 16);
}
__device__ __forceinline__ float bf2f(ushort h) {
  uint32_t u = ((uint32_t)h) << 16;
  return __builtin_bit_cast(float, u);
}
__device__ __forceinline__ float sigm(float x) { return 1.f / (1.f + __expf(-x)); }
__device__ __forceinline__ float tanh_f(float x) { return 1.f - 2.f / (__expf(2.f * x) + 1.f); }
__device__ __forceinline__ bf16x8 bc8u(uint4 u) { return __builtin_bit_cast(bf16x8, u); }

__global__ __launch_bounds__(256) void report_ws(float* __restrict__ out, int n, float val) {
  int i = blockIdx.x * 256 + threadIdx.x;
  if (i < n) out[i] = val;
}

__global__ __launch_bounds__(256) void pack_emb(const float* __restrict__ emb,
                                                ushort* __restrict__ embB) {
  int i = blockIdx.x * 256 + threadIdx.x;  // 32768
  embB[i] = f2bf(emb[i]);
}

// Frag-packed W (r9/r10/r13 layout). Slice (d, nb) = 2*KSL frags of 1KB.
// frag f = kslg*2 + n2; elem (l,e): rloc = n2*16 + (l&15);
// grow = (rloc>>3)*512 + nb*8 + (rloc&7); k = kslg*32 + (l>>4)*8 + e.
// k<512 -> Whh[d][grow][k]; else Wih[d][grow][k-512].
__global__ __launch_bounds__(256) void pack_w(const float* __restrict__ Whh,
                                              const float* __restrict__ Wih,
                                              ushort* __restrict__ Wp,
                                              int KSL, int Ein) {
  size_t idx = (size_t)blockIdx.x * 256 + threadIdx.x;
  size_t total = (size_t)128 * 2 * KSL * 512;
  if (idx >= total) return;
  int e = (int)(idx & 7);
  int l = (int)((idx >> 3) & 63);
  int f = (int)((idx >> 9) % (size_t)(2 * KSL));
  int sl = (int)(idx / ((size_t)1024 * KSL));
  int nb = sl & 63, d = sl >> 6;
  int n2 = f & 1, kslg = f >> 1;
  int rloc = n2 * 16 + (l & 15);
  int grow = (rloc >> 3) * 512 + nb * 8 + (rloc & 7);
  int k = kslg * 32 + (l >> 4) * 8 + e;
  float val;
  if (k < 512) val = Whh[((size_t)d * 2048 + grow) * 512 + k];
  else         val = Wih[((size_t)d * 2048 + grow) * Ein + (k - 512)];
  Wp[idx] = f2bf(val);
}

__global__ __launch_bounds__(256) void pack_wout(const float* __restrict__ Wo,
                                                 ushort* __restrict__ WoB) {
  int i = blockIdx.x * 256 + threadIdx.x;  // 131072
  WoB[i] = f2bf(Wo[i]);
}

// zero hpk (1MB = 65536 uint4) + barrier slots (512 u32)
__global__ __launch_bounds__(256) void zero_h(unsigned int* __restrict__ hpk,
                                              unsigned int* __restrict__ bars) {
  int i = blockIdx.x * 256 + threadIdx.x;  // grid 256
  ((uint4*)hpk)[i] = make_uint4(0, 0, 0, 0);
  if (i < 512) bars[i] = 0;
}

// ---------------------------------------------------------------------------
// Projection chunk (r10/r13-validated): WG -> t = base(dirp, k)+slot, rows
// bh*64..+63, all 128 v, K=512. k<=3: write (+bout); k>=4: atomic add.
// ---------------------------------------------------------------------------
__device__ void proj_body(int k, int slot, int dirp, int bh, int tid,
                          const ushort* __restrict__ ring,
                          const ushort* __restrict__ WoB,
                          const float* __restrict__ bout,
                          float* __restrict__ out, char* shm) {
  const int tp = (dirp ? (448 - 64 * k) : (64 * k)) + slot;
  const int mode = (k >= 4);
  ushort* As = (ushort*)shm;            // [64][32] swizzled 64B rows
  ushort* Bs = (ushort*)(shm + 4096);   // [128][32] swizzled
  const int wm = tid >> 6;
  const int lane = tid & 63;

  f32x4 acc[8] = {};

  for (int kt = 0; kt < 16; ++kt) {     // K = 512
    const int rA = tid >> 2, qA = tid & 3;
    uint4 ra = *(const uint4*)(ring + ((size_t)(dirp * 64 + slot) * BB + bh * 64 + rA) * HH +
                               kt * 32 + qA * 8);
    uint4 rb[2];
#pragma unroll
    for (int it = 0; it < 2; ++it) {
      int c = it * 256 + tid;
      int rB = c >> 2, qB = c & 3;
      rb[it] = *(const uint4*)(WoB + (size_t)rB * 1024 + dirp * HH + kt * 32 + qB * 8);
    }
    __syncthreads();
    *(uint4*)((char*)As + rA * 64 + ((qA << 4) ^ ((rA & 3) << 4))) = ra;
#pragma unroll
    for (int it = 0; it < 2; ++it) {
      int c = it * 256 + tid;
      int rB = c >> 2, qB = c & 3;
      *(uint4*)((char*)Bs + rB * 64 + ((qB << 4) ^ ((rB & 3) << 4))) = rb[it];
    }
    __syncthreads();
    const int kb = (lane >> 4) << 4;
    const int rowa = wm * 16 + (lane & 15);
    bf16x8 a = *(const bf16x8*)((const char*)As + rowa * 64 + (kb ^ ((rowa & 3) << 4)));
#pragma unroll
    for (int n = 0; n < 8; ++n) {
      int rowb = n * 16 + (lane & 15);
      bf16x8 b = *(const bf16x8*)((const char*)Bs + rowb * 64 + (kb ^ ((rowb & 3) << 4)));
      acc[n] = __builtin_amdgcn_mfma_f32_16x16x32_bf16(a, b, acc[n], 0, 0, 0);
    }
  }

  const int rbase = (lane >> 4) * 4;
#pragma unroll
  for (int n = 0; n < 8; ++n) {
    int v = n * 16 + (lane & 15);
    float bo = bout[v];
#pragma unroll
    for (int r = 0; r < 4; ++r) {
      int b = bh * 64 + wm * 16 + rbase + r;
      size_t o = ((size_t)b * TT + tp) * VV + v;
      if (mode) (void)unsafeAtomicAdd(&out[o], acc[n][r]);
      else      __hip_atomic_store(&out[o], acc[n][r] + bo, __ATOMIC_RELAXED, AGENT);
    }
  }
}

// ---------------------------------------------------------------------------
// Persistent LSTM layer (r13 kernel, full range, HMODE=1 + BMODE=1).
// 256 WGs = (dir 2)(nb 64)(mh 2), 256 threads.
// h via sc1 u64 atomic loads (LLC); NO per-step invalidates; scope-64
// busy-poll flag wait; x_phase in the wait shadow.
// ---------------------------------------------------------------------------
template <int IS_L0, int XS, int KSL>
__global__ __launch_bounds__(256, 1) void lstm_persist(
    const ushort* __restrict__ Wp,    // [128 slices][2*KSL frags][512]
    ushort* __restrict__ hseq,        // [T][B][1024]: L0 writes (sc1), L1 x-in
    const int* __restrict__ sent,     // L0: [B][T]
    const ushort* __restrict__ embB,  // L0: [128][256]
    unsigned int* __restrict__ hpk,   // [2 par][2 dir][2 pl][128][256] u32
    ushort* __restrict__ ring,        // L1: [2][64][B][512]
    const ushort* __restrict__ WoB,   // L1: [V][1024]
    const float* __restrict__ bout,   // L1: [V]
    float* __restrict__ out,          // L1: [B][T][V]
    const float* __restrict__ bih, const float* __restrict__ bhh,
    unsigned int* __restrict__ bars) {
  const int wg = blockIdx.x;          // (dir<<7) | (nb<<1) | mh
  const int mh = wg & 1;
  const int nb = (wg >> 1) & 63;
  const int dir = wg >> 7;
  const int tid = threadIdx.x;
  const int wm = tid >> 6;
  const int lane = tid & 63;

  __shared__ __align__(16) char smem[KSL * 2048 + 12544];

  // ---- preload full W slice into LDS
  {
    const uint4* wsrc = (const uint4*)(Wp + (size_t)(dir * 64 + nb) * (2 * KSL * 512));
    for (int i = tid; i < KSL * 128; i += 256)
      ((uint4*)smem)[i] = wsrc[i];
  }
  __syncthreads();

  float* exch = (float*)(smem + KSL * 2048);   // [64][33] f32

  const int arow = mh * 64 + wm * 16 + (lane & 15);  // global batch row (A)
  const int ksub = lane >> 4;

  const int ju = nb * 8 + (lane & 7);
  const float biJ = bih[dir * 2048 + ju] + bhh[dir * 2048 + ju];
  const float bfJ = bih[dir * 2048 + 512 + ju] + bhh[dir * 2048 + 512 + ju];
  const float bgJ = bih[dir * 2048 + 1024 + ju] + bhh[dir * 2048 + 1024 + ju];
  const float boJ = bih[dir * 2048 + 1536 + ju] + bhh[dir * 2048 + 1536 + ju];
  const float bias0 = (lane & 8) ? bfJ : biJ;
  const float bias1 = (lane & 8) ? boJ : bgJ;

  float cst0 = 0.f, cst1 = 0.f;        // c for (row tid>>2, units 2q, 2q+1)
  unsigned int* stepslot = bars;        // [256]
  unsigned int* pslot = bars + 256;     // [256]

  f32x4 acc0, acc1;

  // x-part: acc = bias + x(t) @ Wih^T
  auto x_phase = [&](int t) {
    acc0 = (f32x4){bias0, bias0, bias0, bias0};
    acc1 = (f32x4){bias1, bias1, bias1, bias1};
    const ushort* xr;
    if constexpr (IS_L0) xr = embB + sent[arow * TT + t] * 256 + ksub * 8;
    else                 xr = hseq + ((size_t)t * BB + arow) * 1024 + ksub * 8;
    uint4 xa[XS];
#pragma unroll
    for (int i = 0; i < XS; ++i) xa[i] = *(const uint4*)(xr + i * 32);
#pragma unroll
    for (int i = 0; i < XS; ++i) {
      bf16x8 b0 = *(const bf16x8*)(smem + (16 + i) * 2048 + (lane << 4));
      bf16x8 b1 = *(const bf16x8*)(smem + (16 + i) * 2048 + 1024 + (lane << 4));
      acc0 = __builtin_amdgcn_mfma_f32_16x16x32_bf16(bc8u(xa[i]), b0, acc0, 0, 0, 0);
      acc1 = __builtin_amdgcn_mfma_f32_16x16x32_bf16(bc8u(xa[i]), b1, acc1, 0, 0, 0);
    }
  };

  // h-part: acc += Whh*(hi + lo); sc1 u64 atomic loads (LLC; r9/r13-proven)
  auto h_phase = [&](int par) {
    uint4 ahi[16], alo[16];
    const unsigned long long* hb64 = (const unsigned long long*)hpk +
                                     (size_t)par * 65536 + (size_t)dir * 32768 +
                                     (size_t)arow * 128 + ksub * 2;
#pragma unroll
    for (int ks = 0; ks < 16; ++ks) {
      unsigned long long a0 = __hip_atomic_load(hb64 + ks * 8, __ATOMIC_RELAXED, AGENT);
      unsigned long long a1 = __hip_atomic_load(hb64 + ks * 8 + 1, __ATOMIC_RELAXED, AGENT);
      ahi[ks] = make_uint4((uint32_t)a0, (uint32_t)(a0 >> 32),
                           (uint32_t)a1, (uint32_t)(a1 >> 32));
    }
#pragma unroll
    for (int ks = 0; ks < 16; ++ks) {
      unsigned long long a0 =
          __hip_atomic_load(hb64 + 16384 + ks * 8, __ATOMIC_RELAXED, AGENT);
      unsigned long long a1 =
          __hip_atomic_load(hb64 + 16384 + ks * 8 + 1, __ATOMIC_RELAXED, AGENT);
      alo[ks] = make_uint4((uint32_t)a0, (uint32_t)(a0 >> 32),
                           (uint32_t)a1, (uint32_t)(a1 >> 32));
    }
#pragma unroll
    for (int ks = 0; ks < 16; ++ks) {
      bf16x8 b0 = *(const bf16x8*)(smem + ks * 2048 + (lane << 4));
      bf16x8 b1 = *(const bf16x8*)(smem + ks * 2048 + 1024 + (lane << 4));
      acc0 = __builtin_amdgcn_mfma_f32_16x16x32_bf16(bc8u(ahi[ks]), b0, acc0, 0, 0, 0);
      acc1 = __builtin_amdgcn_mfma_f32_16x16x32_bf16(bc8u(ahi[ks]), b1, acc1, 0, 0, 0);
      acc0 = __builtin_amdgcn_mfma_f32_16x16x32_bf16(bc8u(alo[ks]), b0, acc0, 0, 0, 0);
      acc1 = __builtin_amdgcn_mfma_f32_16x16x32_bf16(bc8u(alo[ks]), b1, acc1, 0, 0, 0);
    }
  };

  // prologue: x-part for step 0
  x_phase(dir ? TT - 1 : 0);

  for (int s = 0; s < TT; ++s) {
    const int t = dir ? (TT - 1 - s) : s;

    // ---- wait for h(s): scope-64 (same dir+mh) busy poll (r13 BMODE=1)
    if (tid < 64) {
      while (__hip_atomic_load(&stepslot[dir * 128 + (tid << 1) + mh],
                               __ATOMIC_RELAXED, AGENT) < (unsigned)s) {}
    }
    __syncthreads();

    h_phase(s & 1);

    // ---- gate exchange through LDS [64][33] f32
    {
      const int rb4 = (lane >> 4) * 4;
#pragma unroll
      for (int r = 0; r < 4; ++r) {
        int lr = wm * 16 + rb4 + r;
        exch[lr * 33 + (lane & 15)]      = acc0[r];
        exch[lr * 33 + 16 + (lane & 15)] = acc1[r];
      }
    }
    __syncthreads();

    // ---- epilogue: thread (lr = tid>>2, q = tid&3) owns units 2q, 2q+1
    {
      const int lr = tid >> 2;
      const int q = tid & 3;
      ushort hh[2], hl[2];
#pragma unroll
      for (int i = 0; i < 2; ++i) {
        const int u = q * 2 + i;
        float gi = exch[lr * 33 + u];
        float gf = exch[lr * 33 + 8 + u];
        float gg = exch[lr * 33 + 16 + u];
        float go = exch[lr * 33 + 24 + u];
        float si = sigm(gi), sf = sigm(gf), tg = tanh_f(gg), so = sigm(go);
        float c = sf * (i ? cst1 : cst0) + si * tg;
        (i ? cst1 : cst0) = c;
        float h = so * tanh_f(c);
        hh[i] = f2bf(h);
        hl[i] = f2bf(h - bf2f(hh[i]));
      }
      const int b = mh * 64 + lr;
      const uint32_t vhi = (uint32_t)hh[0] | ((uint32_t)hh[1] << 16);
      const uint32_t vlo = (uint32_t)hl[0] | ((uint32_t)hl[1] << 16);
      unsigned int* hw = hpk + (size_t)((s & 1) ^ 1) * 131072 + (size_t)dir * 65536;
      __hip_atomic_store(hw + (size_t)b * 256 + nb * 4 + q, vhi, __ATOMIC_RELAXED, AGENT);
      __hip_atomic_store(hw + 32768 + (size_t)b * 256 + nb * 4 + q, vlo,
                         __ATOMIC_RELAXED, AGENT);
      if constexpr (IS_L0) {
        __hip_atomic_store((unsigned int*)hseq + ((size_t)t * BB + b) * 512 +
                               dir * 256 + nb * 4 + q,
                           vhi, __ATOMIC_RELAXED, AGENT);
      } else {
        __hip_atomic_store((unsigned int*)ring +
                               ((size_t)(dir * 64 + (t & 63)) * BB + b) * 256 + nb * 4 + q,
                           vhi, __ATOMIC_RELAXED, AGENT);
      }
    }

    __syncthreads();  // drain stores (vmcnt 0) + protect exch
    if (tid == 0)
      __hip_atomic_store(&stepslot[wg], (unsigned)(s + 1), __ATOMIC_RELAXED, AGENT);

    // x-part for step s+1 in the wait shadow
    if (s + 1 < TT) x_phase(dir ? (TT - 2 - s) : (s + 1));

    if constexpr (!IS_L0) {
      if ((s & 63) == 63) {
        // all 256 WGs published this chunk; ACQUIRE (L2 inv) for plain ring
        // reads (ring is sc1-written -> L2 clean -> inv-safe; r10/r13-proven)
        {
          const unsigned tgt = (unsigned)(s + 1);
          while (__hip_atomic_load(&stepslot[tid], __ATOMIC_RELAXED, AGENT) < tgt)
            __builtin_amdgcn_s_sleep(1);
        }
        __syncthreads();
        if (tid == 0) (void)__hip_atomic_load(&stepslot[0], __ATOMIC_ACQUIRE, AGENT);
        __syncthreads();
        proj_body(s >> 6, wg & 63, (wg >> 6) & 1, wg >> 7, tid, ring, WoB, bout, out,
                  smem + KSL * 2048);
        __syncthreads();  // proj loads drained before ring reuse
        const unsigned ptg = (unsigned)((s >> 6) + 1);
        if (tid == 0)
          __hip_atomic_store(pslot + wg, ptg, __ATOMIC_RELAXED, AGENT);
        while (__hip_atomic_load(pslot + tid, __ATOMIC_RELAXED, AGENT) < ptg)
          __builtin_amdgcn_s_sleep(1);
        __syncthreads();
      }
    }
  }
}

// ---------------------------------------------------------------------------
extern "C" void kernel_launch(void* const* d_in, const int* in_sizes, int n_in,
                              void* d_out, int out_size, void* d_ws, size_t ws_size,
                              hipStream_t stream) {
  const int* sent = (const int*)d_in[0];
  const float* emb = (const float*)d_in[1];
  const float* Wih0 = (const float*)d_in[2];
  const float* Whh0 = (const float*)d_in[3];
  const float* bih0 = (const float*)d_in[4];
  const float* bhh0 = (const float*)d_in[5];
  const float* Wih1 = (const float*)d_in[6];
  const float* Whh1 = (const float*)d_in[7];
  const float* bih1 = (const float*)d_in[8];
  const float* bhh1 = (const float*)d_in[9];
  const float* Wout = (const float*)d_in[10];
  const float* bout = (const float*)d_in[11];
  float* out = (float*)d_out;

  // ws layout (bytes); total 171,247,616
  const size_t NEED = 171247616;
  if (ws_size < NEED) {
    report_ws<<<(out_size + 255) / 256, 256, 0, stream>>>(out, out_size,
                                                          (float)(ws_size >> 20));
    return;
  }
  char* ws = (char*)d_ws;
  ushort* h0   = (ushort*)(ws + 0);                 // 134,217,728  [T][B][1024]
  ushort* Wp0  = (ushort*)(ws + 134217728);         //   6,291,456  KSL=24
  ushort* Wp1  = (ushort*)(ws + 140509184);         //  12,582,912  KSL=48
  ushort* WoB  = (ushort*)(ws + 153092096);         //     262,144
  ushort* embB = (ushort*)(ws + 153354240);         //      65,536
  unsigned int* hpk = (unsigned int*)(ws + 153419776); // 1,048,576
  ushort* ring = (ushort*)(ws + 154468352);         //   8,388,608  [2][64][B][512]
  unsigned int* bars = (unsigned int*)(ws + 171245568);  // 2048B (512 u32)

  pack_emb<<<128, 256, 0, stream>>>(emb, embB);
  pack_w<<<12288, 256, 0, stream>>>(Whh0, Wih0, Wp0, 24, 256);
  pack_w<<<24576, 256, 0, stream>>>(Whh1, Wih1, Wp1, 48, 1024);
  pack_wout<<<512, 256, 0, stream>>>(Wout, WoB);

  // layer 0 (persistent, 256 WGs)
  zero_h<<<256, 256, 0, stream>>>(hpk, bars);
  lstm_persist<1, 8, 24><<<256, 256, 0, stream>>>(
      Wp0, h0, sent, embB, hpk, ring, WoB, bout, out, bih0, bhh0, bars);

  // layer 1 (persistent, proj folded in)
  zero_h<<<256, 256, 0, stream>>>(hpk, bars);
  lstm_persist<0, 32, 48><<<256, 256, 0, stream>>>(
      Wp1, h0, sent, embB, hpk, ring, WoB, bout, out, bih1, bhh1, bars);
}

// Round 19
// 8250.979 us; speedup vs baseline: 1.4426x; 1.4426x over previous
//
#include <hip/hip_runtime.h>
#include <stdint.h>

// ---------------------------------------------------------------------------
// 2-layer BiLSTM LM: emb -> BiLSTM(E=256->H=512) -> BiLSTM(1024->512) -> proj
// V=128 E=256 H=512 B=128 T=512.
//
// Round 19 = r18 (PASSED, 11.9ms) with SINGLE-PLANE h (hi/lo split dropped).
//  Rationale: five null A/Bs (coherence mode, inv policy, barrier scope,
//  poll style, window-inv) show the step is pinned by serialized LLC round
//  trips, not their flavor. The one untested step-time term is h VOLUME:
//  hi/lo doubles loads (64 u64), MFMAs (128/step), and publish stores.
//  Cross-layer paths already use single-bf16 h (hseq/ring store vhi only)
//  and pass at 1.95e-3 with 3.9x headroom; recurrent-path rounding enters
//  through contracting gates. Risk: absmax may grow to ~3-5e-3 (thr 7.6e-3).
//  - hpk: [2 par][2 dir][128 b][256 u32] (hi only), 512KB.
//  - h_phase: 32 u64 sc1 loads, 32 MFMAs (was 64/64+64).
//  - epilogue: single vhi store (lo dropped).
//  - everything else byte-identical to r18 (no invs, scope-64 busy poll,
//    x-in-shadow, proj w/ ACQUIRE every 64 steps).
// ---------------------------------------------------------------------------

#define TT 512
#define BB 128
#define HH 512
#define VV 128
#define AGENT __HIP_MEMORY_SCOPE_AGENT

typedef __attribute__((ext_vector_type(8))) short bf16x8;
typedef __attribute__((ext_vector_type(4))) float f32x4;

__device__ __forceinline__ ushort f2bf(float f) {
  uint32_t u = __builtin_bit_cast(uint32_t, f);
  u += 0x7FFFu + ((u >> 16) & 1u);
  return (ushort)(u >> 16);
}
__device__ __forceinline__ float sigm(float x) { return 1.f / (1.f + __expf(-x)); }
__device__ __forceinline__ float tanh_f(float x) { return 1.f - 2.f / (__expf(2.f * x) + 1.f); }
__device__ __forceinline__ bf16x8 bc8u(uint4 u) { return __builtin_bit_cast(bf16x8, u); }

__global__ __launch_bounds__(256) void report_ws(float* __restrict__ out, int n, float val) {
  int i = blockIdx.x * 256 + threadIdx.x;
  if (i < n) out[i] = val;
}

__global__ __launch_bounds__(256) void pack_emb(const float* __restrict__ emb,
                                                ushort* __restrict__ embB) {
  int i = blockIdx.x * 256 + threadIdx.x;  // 32768
  embB[i] = f2bf(emb[i]);
}

// Frag-packed W (r9/r10/r13/r18 layout). Slice (d, nb) = 2*KSL frags of 1KB.
// frag f = kslg*2 + n2; elem (l,e): rloc = n2*16 + (l&15);
// grow = (rloc>>3)*512 + nb*8 + (rloc&7); k = kslg*32 + (l>>4)*8 + e.
// k<512 -> Whh[d][grow][k]; else Wih[d][grow][k-512].
__global__ __launch_bounds__(256) void pack_w(const float* __restrict__ Whh,
                                              const float* __restrict__ Wih,
                                              ushort* __restrict__ Wp,
                                              int KSL, int Ein) {
  size_t idx = (size_t)blockIdx.x * 256 + threadIdx.x;
  size_t total = (size_t)128 * 2 * KSL * 512;
  if (idx >= total) return;
  int e = (int)(idx & 7);
  int l = (int)((idx >> 3) & 63);
  int f = (int)((idx >> 9) % (size_t)(2 * KSL));
  int sl = (int)(idx / ((size_t)1024 * KSL));
  int nb = sl & 63, d = sl >> 6;
  int n2 = f & 1, kslg = f >> 1;
  int rloc = n2 * 16 + (l & 15);
  int grow = (rloc >> 3) * 512 + nb * 8 + (rloc & 7);
  int k = kslg * 32 + (l >> 4) * 8 + e;
  float val;
  if (k < 512) val = Whh[((size_t)d * 2048 + grow) * 512 + k];
  else         val = Wih[((size_t)d * 2048 + grow) * Ein + (k - 512)];
  Wp[idx] = f2bf(val);
}

__global__ __launch_bounds__(256) void pack_wout(const float* __restrict__ Wo,
                                                 ushort* __restrict__ WoB) {
  int i = blockIdx.x * 256 + threadIdx.x;  // 131072
  WoB[i] = f2bf(Wo[i]);
}

// zero hpk (512KB = 32768 uint4) + barrier slots (512 u32)
__global__ __launch_bounds__(256) void zero_h(unsigned int* __restrict__ hpk,
                                              unsigned int* __restrict__ bars) {
  int i = blockIdx.x * 256 + threadIdx.x;  // grid 128 -> 32768
  ((uint4*)hpk)[i] = make_uint4(0, 0, 0, 0);
  if (i < 512) bars[i] = 0;
}

// ---------------------------------------------------------------------------
// Projection chunk (r10/r13/r18-validated): WG -> t = base(dirp, k)+slot,
// rows bh*64..+63, all 128 v, K=512. k<=3: write (+bout); k>=4: atomic add.
// ---------------------------------------------------------------------------
__device__ void proj_body(int k, int slot, int dirp, int bh, int tid,
                          const ushort* __restrict__ ring,
                          const ushort* __restrict__ WoB,
                          const float* __restrict__ bout,
                          float* __restrict__ out, char* shm) {
  const int tp = (dirp ? (448 - 64 * k) : (64 * k)) + slot;
  const int mode = (k >= 4);
  ushort* As = (ushort*)shm;            // [64][32] swizzled 64B rows
  ushort* Bs = (ushort*)(shm + 4096);   // [128][32] swizzled
  const int wm = tid >> 6;
  const int lane = tid & 63;

  f32x4 acc[8] = {};

  for (int kt = 0; kt < 16; ++kt) {     // K = 512
    const int rA = tid >> 2, qA = tid & 3;
    uint4 ra = *(const uint4*)(ring + ((size_t)(dirp * 64 + slot) * BB + bh * 64 + rA) * HH +
                               kt * 32 + qA * 8);
    uint4 rb[2];
#pragma unroll
    for (int it = 0; it < 2; ++it) {
      int c = it * 256 + tid;
      int rB = c >> 2, qB = c & 3;
      rb[it] = *(const uint4*)(WoB + (size_t)rB * 1024 + dirp * HH + kt * 32 + qB * 8);
    }
    __syncthreads();
    *(uint4*)((char*)As + rA * 64 + ((qA << 4) ^ ((rA & 3) << 4))) = ra;
#pragma unroll
    for (int it = 0; it < 2; ++it) {
      int c = it * 256 + tid;
      int rB = c >> 2, qB = c & 3;
      *(uint4*)((char*)Bs + rB * 64 + ((qB << 4) ^ ((rB & 3) << 4))) = rb[it];
    }
    __syncthreads();
    const int kb = (lane >> 4) << 4;
    const int rowa = wm * 16 + (lane & 15);
    bf16x8 a = *(const bf16x8*)((const char*)As + rowa * 64 + (kb ^ ((rowa & 3) << 4)));
#pragma unroll
    for (int n = 0; n < 8; ++n) {
      int rowb = n * 16 + (lane & 15);
      bf16x8 b = *(const bf16x8*)((const char*)Bs + rowb * 64 + (kb ^ ((rowb & 3) << 4)));
      acc[n] = __builtin_amdgcn_mfma_f32_16x16x32_bf16(a, b, acc[n], 0, 0, 0);
    }
  }

  const int rbase = (lane >> 4) * 4;
#pragma unroll
  for (int n = 0; n < 8; ++n) {
    int v = n * 16 + (lane & 15);
    float bo = bout[v];
#pragma unroll
    for (int r = 0; r < 4; ++r) {
      int b = bh * 64 + wm * 16 + rbase + r;
      size_t o = ((size_t)b * TT + tp) * VV + v;
      if (mode) (void)unsafeAtomicAdd(&out[o], acc[n][r]);
      else      __hip_atomic_store(&out[o], acc[n][r] + bo, __ATOMIC_RELAXED, AGENT);
    }
  }
}

// ---------------------------------------------------------------------------
// Persistent LSTM layer (r18 kernel, single-plane h).
// 256 WGs = (dir 2)(nb 64)(mh 2), 256 threads.
// ---------------------------------------------------------------------------
template <int IS_L0, int XS, int KSL>
__global__ __launch_bounds__(256, 1) void lstm_persist(
    const ushort* __restrict__ Wp,    // [128 slices][2*KSL frags][512]
    ushort* __restrict__ hseq,        // [T][B][1024]: L0 writes (sc1), L1 x-in
    const int* __restrict__ sent,     // L0: [B][T]
    const ushort* __restrict__ embB,  // L0: [128][256]
    unsigned int* __restrict__ hpk,   // [2 par][2 dir][128][256] u32 (hi only)
    ushort* __restrict__ ring,        // L1: [2][64][B][512]
    const ushort* __restrict__ WoB,   // L1: [V][1024]
    const float* __restrict__ bout,   // L1: [V]
    float* __restrict__ out,          // L1: [B][T][V]
    const float* __restrict__ bih, const float* __restrict__ bhh,
    unsigned int* __restrict__ bars) {
  const int wg = blockIdx.x;          // (dir<<7) | (nb<<1) | mh
  const int mh = wg & 1;
  const int nb = (wg >> 1) & 63;
  const int dir = wg >> 7;
  const int tid = threadIdx.x;
  const int wm = tid >> 6;
  const int lane = tid & 63;

  __shared__ __align__(16) char smem[KSL * 2048 + 12544];

  // ---- preload full W slice into LDS
  {
    const uint4* wsrc = (const uint4*)(Wp + (size_t)(dir * 64 + nb) * (2 * KSL * 512));
    for (int i = tid; i < KSL * 128; i += 256)
      ((uint4*)smem)[i] = wsrc[i];
  }
  __syncthreads();

  float* exch = (float*)(smem + KSL * 2048);   // [64][33] f32

  const int arow = mh * 64 + wm * 16 + (lane & 15);  // global batch row (A)
  const int ksub = lane >> 4;

  const int ju = nb * 8 + (lane & 7);
  const float biJ = bih[dir * 2048 + ju] + bhh[dir * 2048 + ju];
  const float bfJ = bih[dir * 2048 + 512 + ju] + bhh[dir * 2048 + 512 + ju];
  const float bgJ = bih[dir * 2048 + 1024 + ju] + bhh[dir * 2048 + 1024 + ju];
  const float boJ = bih[dir * 2048 + 1536 + ju] + bhh[dir * 2048 + 1536 + ju];
  const float bias0 = (lane & 8) ? bfJ : biJ;
  const float bias1 = (lane & 8) ? boJ : bgJ;

  float cst0 = 0.f, cst1 = 0.f;        // c for (row tid>>2, units 2q, 2q+1)
  unsigned int* stepslot = bars;        // [256]
  unsigned int* pslot = bars + 256;     // [256]

  f32x4 acc0, acc1;

  // x-part: acc = bias + x(t) @ Wih^T
  auto x_phase = [&](int t) {
    acc0 = (f32x4){bias0, bias0, bias0, bias0};
    acc1 = (f32x4){bias1, bias1, bias1, bias1};
    const ushort* xr;
    if constexpr (IS_L0) xr = embB + sent[arow * TT + t] * 256 + ksub * 8;
    else                 xr = hseq + ((size_t)t * BB + arow) * 1024 + ksub * 8;
    uint4 xa[XS];
#pragma unroll
    for (int i = 0; i < XS; ++i) xa[i] = *(const uint4*)(xr + i * 32);
#pragma unroll
    for (int i = 0; i < XS; ++i) {
      bf16x8 b0 = *(const bf16x8*)(smem + (16 + i) * 2048 + (lane << 4));
      bf16x8 b1 = *(const bf16x8*)(smem + (16 + i) * 2048 + 1024 + (lane << 4));
      acc0 = __builtin_amdgcn_mfma_f32_16x16x32_bf16(bc8u(xa[i]), b0, acc0, 0, 0, 0);
      acc1 = __builtin_amdgcn_mfma_f32_16x16x32_bf16(bc8u(xa[i]), b1, acc1, 0, 0, 0);
    }
  };

  // h-part: acc += Whh*h (single bf16 plane); sc1 u64 atomic loads (LLC)
  auto h_phase = [&](int par) {
    uint4 ah[16];
    const unsigned long long* hb64 = (const unsigned long long*)hpk +
                                     (size_t)par * 32768 + (size_t)dir * 16384 +
                                     (size_t)arow * 128 + ksub * 2;
#pragma unroll
    for (int ks = 0; ks < 16; ++ks) {
      unsigned long long a0 = __hip_atomic_load(hb64 + ks * 8, __ATOMIC_RELAXED, AGENT);
      unsigned long long a1 = __hip_atomic_load(hb64 + ks * 8 + 1, __ATOMIC_RELAXED, AGENT);
      ah[ks] = make_uint4((uint32_t)a0, (uint32_t)(a0 >> 32),
                          (uint32_t)a1, (uint32_t)(a1 >> 32));
    }
#pragma unroll
    for (int ks = 0; ks < 16; ++ks) {
      bf16x8 b0 = *(const bf16x8*)(smem + ks * 2048 + (lane << 4));
      bf16x8 b1 = *(const bf16x8*)(smem + ks * 2048 + 1024 + (lane << 4));
      acc0 = __builtin_amdgcn_mfma_f32_16x16x32_bf16(bc8u(ah[ks]), b0, acc0, 0, 0, 0);
      acc1 = __builtin_amdgcn_mfma_f32_16x16x32_bf16(bc8u(ah[ks]), b1, acc1, 0, 0, 0);
    }
  };

  // prologue: x-part for step 0
  x_phase(dir ? TT - 1 : 0);

  for (int s = 0; s < TT; ++s) {
    const int t = dir ? (TT - 1 - s) : s;

    // ---- wait for h(s): scope-64 (same dir+mh) busy poll (r13/r18)
    if (tid < 64) {
      while (__hip_atomic_load(&stepslot[dir * 128 + (tid << 1) + mh],
                               __ATOMIC_RELAXED, AGENT) < (unsigned)s) {}
    }
    __syncthreads();

    h_phase(s & 1);

    // ---- gate exchange through LDS [64][33] f32
    {
      const int rb4 = (lane >> 4) * 4;
#pragma unroll
      for (int r = 0; r < 4; ++r) {
        int lr = wm * 16 + rb4 + r;
        exch[lr * 33 + (lane & 15)]      = acc0[r];
        exch[lr * 33 + 16 + (lane & 15)] = acc1[r];
      }
    }
    __syncthreads();

    // ---- epilogue: thread (lr = tid>>2, q = tid&3) owns units 2q, 2q+1
    {
      const int lr = tid >> 2;
      const int q = tid & 3;
      ushort hh[2];
#pragma unroll
      for (int i = 0; i < 2; ++i) {
        const int u = q * 2 + i;
        float gi = exch[lr * 33 + u];
        float gf = exch[lr * 33 + 8 + u];
        float gg = exch[lr * 33 + 16 + u];
        float go = exch[lr * 33 + 24 + u];
        float si = sigm(gi), sf = sigm(gf), tg = tanh_f(gg), so = sigm(go);
        float c = sf * (i ? cst1 : cst0) + si * tg;
        (i ? cst1 : cst0) = c;
        float h = so * tanh_f(c);
        hh[i] = f2bf(h);
      }
      const int b = mh * 64 + lr;
      const uint32_t vhi = (uint32_t)hh[0] | ((uint32_t)hh[1] << 16);
      unsigned int* hw = hpk + (size_t)((s & 1) ^ 1) * 65536 + (size_t)dir * 32768;
      __hip_atomic_store(hw + (size_t)b * 256 + nb * 4 + q, vhi, __ATOMIC_RELAXED, AGENT);
      if constexpr (IS_L0) {
        __hip_atomic_store((unsigned int*)hseq + ((size_t)t * BB + b) * 512 +
                               dir * 256 + nb * 4 + q,
                           vhi, __ATOMIC_RELAXED, AGENT);
      } else {
        __hip_atomic_store((unsigned int*)ring +
                               ((size_t)(dir * 64 + (t & 63)) * BB + b) * 256 + nb * 4 + q,
                           vhi, __ATOMIC_RELAXED, AGENT);
      }
    }

    __syncthreads();  // drain stores (vmcnt 0) + protect exch
    if (tid == 0)
      __hip_atomic_store(&stepslot[wg], (unsigned)(s + 1), __ATOMIC_RELAXED, AGENT);

    // x-part for step s+1 in the wait shadow
    if (s + 1 < TT) x_phase(dir ? (TT - 2 - s) : (s + 1));

    if constexpr (!IS_L0) {
      if ((s & 63) == 63) {
        // all 256 WGs published this chunk; ACQUIRE (L2 inv) for plain ring
        // reads (ring is sc1-written -> L2 clean -> inv-safe)
        {
          const unsigned tgt = (unsigned)(s + 1);
          while (__hip_atomic_load(&stepslot[tid], __ATOMIC_RELAXED, AGENT) < tgt)
            __builtin_amdgcn_s_sleep(1);
        }
        __syncthreads();
        if (tid == 0) (void)__hip_atomic_load(&stepslot[0], __ATOMIC_ACQUIRE, AGENT);
        __syncthreads();
        proj_body(s >> 6, wg & 63, (wg >> 6) & 1, wg >> 7, tid, ring, WoB, bout, out,
                  smem + KSL * 2048);
        __syncthreads();  // proj loads drained before ring reuse
        const unsigned ptg = (unsigned)((s >> 6) + 1);
        if (tid == 0)
          __hip_atomic_store(pslot + wg, ptg, __ATOMIC_RELAXED, AGENT);
        while (__hip_atomic_load(pslot + tid, __ATOMIC_RELAXED, AGENT) < ptg)
          __builtin_amdgcn_s_sleep(1);
        __syncthreads();
      }
    }
  }
}

// ---------------------------------------------------------------------------
extern "C" void kernel_launch(void* const* d_in, const int* in_sizes, int n_in,
                              void* d_out, int out_size, void* d_ws, size_t ws_size,
                              hipStream_t stream) {
  const int* sent = (const int*)d_in[0];
  const float* emb = (const float*)d_in[1];
  const float* Wih0 = (const float*)d_in[2];
  const float* Whh0 = (const float*)d_in[3];
  const float* bih0 = (const float*)d_in[4];
  const float* bhh0 = (const float*)d_in[5];
  const float* Wih1 = (const float*)d_in[6];
  const float* Whh1 = (const float*)d_in[7];
  const float* bih1 = (const float*)d_in[8];
  const float* bhh1 = (const float*)d_in[9];
  const float* Wout = (const float*)d_in[10];
  const float* bout = (const float*)d_in[11];
  float* out = (float*)d_out;

  // ws layout (bytes); total 171,247,616
  const size_t NEED = 171247616;
  if (ws_size < NEED) {
    report_ws<<<(out_size + 255) / 256, 256, 0, stream>>>(out, out_size,
                                                          (float)(ws_size >> 20));
    return;
  }
  char* ws = (char*)d_ws;
  ushort* h0   = (ushort*)(ws + 0);                 // 134,217,728  [T][B][1024]
  ushort* Wp0  = (ushort*)(ws + 134217728);         //   6,291,456  KSL=24
  ushort* Wp1  = (ushort*)(ws + 140509184);         //  12,582,912  KSL=48
  ushort* WoB  = (ushort*)(ws + 153092096);         //     262,144
  ushort* embB = (ushort*)(ws + 153354240);         //      65,536
  unsigned int* hpk = (unsigned int*)(ws + 153419776); // 524,288 (hi only)
  ushort* ring = (ushort*)(ws + 154468352);         //   8,388,608  [2][64][B][512]
  unsigned int* bars = (unsigned int*)(ws + 171245568);  // 2048B (512 u32)

  pack_emb<<<128, 256, 0, stream>>>(emb, embB);
  pack_w<<<12288, 256, 0, stream>>>(Whh0, Wih0, Wp0, 24, 256);
  pack_w<<<24576, 256, 0, stream>>>(Whh1, Wih1, Wp1, 48, 1024);
  pack_wout<<<512, 256, 0, stream>>>(Wout, WoB);

  // layer 0 (persistent, 256 WGs)
  zero_h<<<128, 256, 0, stream>>>(hpk, bars);
  lstm_persist<1, 8, 24><<<256, 256, 0, stream>>>(
      Wp0, h0, sent, embB, hpk, ring, WoB, bout, out, bih0, bhh0, bars);

  // layer 1 (persistent, proj folded in)
  zero_h<<<128, 256, 0, stream>>>(hpk, bars);
  lstm_persist<0, 32, 48><<<256, 256, 0, stream>>>(
      Wp1, h0, sent, embB, hpk, ring, WoB, bout, out, bih1, bhh1, bars);
}